// Round 1
// baseline (687.476 us; speedup 1.0000x reference)
//
#include <hip/hip_runtime.h>
#include <stdint.h>

#define K_DIM 4096
#define N_DIM 4096

typedef __attribute__((ext_vector_type(8))) short s16x8;
typedef __attribute__((ext_vector_type(4))) float f32x4;

static __device__ __forceinline__ unsigned short f32_to_bf16(float f) {
    union { float f; unsigned int u; } v; v.f = f;
    unsigned int u = v.u;
    u += 0x7FFFu + ((u >> 16) & 1u);   // RNE (inputs are finite; no NaN handling needed)
    return (unsigned short)(u >> 16);
}

// ---- x (M,K) f32 -> bf16, straight copy-convert, 8 elems/thread ----
extern "C" __global__ void cvt_bf16_k(const float* __restrict__ in,
                                      unsigned short* __restrict__ out, int n8) {
    int i = blockIdx.x * 256 + threadIdx.x;
    if (i >= n8) return;
    const float4* p = (const float4*)in + (size_t)i * 2;
    float4 a = p[0], b = p[1];
    s16x8 o;
    o[0] = (short)f32_to_bf16(a.x); o[1] = (short)f32_to_bf16(a.y);
    o[2] = (short)f32_to_bf16(a.z); o[3] = (short)f32_to_bf16(a.w);
    o[4] = (short)f32_to_bf16(b.x); o[5] = (short)f32_to_bf16(b.y);
    o[6] = (short)f32_to_bf16(b.z); o[7] = (short)f32_to_bf16(b.w);
    *(s16x8*)(out + (size_t)i * 8) = o;
}

// ---- w_t (K,N) f32 -> (N,K) bf16 transpose-convert, 64x64 tiles ----
extern "C" __global__ void transpose_cvt_k(const float* __restrict__ in,
                                           unsigned short* __restrict__ out) {
    __shared__ unsigned short tile[64][65];  // +1 pad breaks bank conflicts
    int k0 = blockIdx.y * 64, n0 = blockIdx.x * 64;
    int t = threadIdx.x;
    int tr = t >> 4, tc = (t & 15) * 4;
#pragma unroll
    for (int i = 0; i < 4; ++i) {
        int r = tr + i * 16;  // k-local
        float4 v = *(const float4*)(in + (size_t)(k0 + r) * N_DIM + n0 + tc);
        tile[r][tc + 0] = f32_to_bf16(v.x);
        tile[r][tc + 1] = f32_to_bf16(v.y);
        tile[r][tc + 2] = f32_to_bf16(v.z);
        tile[r][tc + 3] = f32_to_bf16(v.w);
    }
    __syncthreads();
#pragma unroll
    for (int i = 0; i < 4; ++i) {
        int r = tr + i * 16;  // n-local
        ushort4 o;
        o.x = tile[tc + 0][r];
        o.y = tile[tc + 1][r];
        o.z = tile[tc + 2][r];
        o.w = tile[tc + 3][r];
        *(ushort4*)(out + (size_t)(n0 + r) * K_DIM + k0 + tc) = o;
    }
}

__device__ __forceinline__ void async_cp16(const unsigned short* g, unsigned short* l) {
    __builtin_amdgcn_global_load_lds(
        (const __attribute__((address_space(1))) unsigned int*)g,
        (__attribute__((address_space(3))) unsigned int*)l, 16, 0, 0);
}

// ---- m97-style GEMM: A (M,K) bf16, B (N,K) bf16, C (M,N) f32 ----
// 128x128 block tile, BK=32, 4 waves each doing 4x4 of 16x16x32 MFMA.
extern "C" __global__ __launch_bounds__(256)
void gemm_bf16_k(const unsigned short* __restrict__ A,
                 const unsigned short* __restrict__ B,
                 float* __restrict__ C, int M) {
    const int K = K_DIM, N = N_DIM;
    // NO padding: global_load_lds lays lanes out contiguously (base + lane*16)
    __shared__ __align__(16) unsigned short sA[128 * 32];
    __shared__ __align__(16) unsigned short sB[128 * 32];
    const int tid = threadIdx.x;
    const int wave = tid >> 6, lane = tid & 63;
    const int wm = (wave >> 1) * 64, wn = (wave & 1) * 64;
    const size_t tileM = (size_t)blockIdx.y * 128, tileN = (size_t)blockIdx.x * 128;
    const int lrow = lane >> 2;        // staging: 4 lanes per 32-elem row
    const int lcol = (lane & 3) * 8;
    const int frow = lane & 15;        // fragment: A[m=lane&15][k=quad*8+j]
    const int fcol = (lane >> 4) * 8;
    f32x4 acc[4][4] = {};

    const unsigned short* gA0 = A + (tileM + wave * 32 + lrow) * (size_t)K + lcol;
    const unsigned short* gA1 = gA0 + 16 * (size_t)K;
    const unsigned short* gB0 = B + (tileN + wave * 32 + lrow) * (size_t)K + lcol;
    const unsigned short* gB1 = gB0 + 16 * (size_t)K;
    unsigned short* lA0 = sA + (wave * 32) * 32;
    unsigned short* lA1 = lA0 + 16 * 32;
    unsigned short* lB0 = sB + (wave * 32) * 32;
    unsigned short* lB1 = lB0 + 16 * 32;

    for (int k0 = 0; k0 < K; k0 += 32) {
        __syncthreads();
        async_cp16(gA0 + k0, lA0);
        async_cp16(gA1 + k0, lA1);
        async_cp16(gB0 + k0, lB0);
        async_cp16(gB1 + k0, lB1);
        __syncthreads();   // compiler emits vmcnt(0) drain before s_barrier
        s16x8 af[4], bfr[4];
#pragma unroll
        for (int i = 0; i < 4; ++i)
            af[i] = *(const s16x8*)(sA + (wm + i * 16 + frow) * 32 + fcol);
#pragma unroll
        for (int j = 0; j < 4; ++j)
            bfr[j] = *(const s16x8*)(sB + (wn + j * 16 + frow) * 32 + fcol);
#pragma unroll
        for (int i = 0; i < 4; ++i)
#pragma unroll
            for (int j = 0; j < 4; ++j)
                acc[i][j] = __builtin_amdgcn_mfma_f32_16x16x32_bf16(
                    af[i], bfr[j], acc[i][j], 0, 0, 0);
    }
    // epilogue: C/D layout col=lane&15, row=(lane>>4)*4+reg (m89-verified)
#pragma unroll
    for (int i = 0; i < 4; ++i)
#pragma unroll
        for (int j = 0; j < 4; ++j) {
            size_t row = tileM + wm + i * 16 + (lane >> 4) * 4;
            size_t col = tileN + wn + j * 16 + (lane & 15);
#pragma unroll
            for (int r = 0; r < 4; ++r)
                C[(row + r) * N + col] = acc[i][j][r];
        }
}

// ---- fallback (ws too small): convert f32->bf16 inline while staging ----
extern "C" __global__ __launch_bounds__(256)
void gemm_f32_k(const float* __restrict__ X,   // (M,K)
                const float* __restrict__ Wt,  // (K,N)
                float* __restrict__ C, int M) {
    const int K = K_DIM, N = N_DIM;
    __shared__ __align__(16) unsigned short sA[128 * 32];
    __shared__ __align__(16) unsigned short sB[128 * 32];
    const int tid = threadIdx.x;
    const int wave = tid >> 6, lane = tid & 63;
    const int wm = (wave >> 1) * 64, wn = (wave & 1) * 64;
    const size_t tileM = (size_t)blockIdx.y * 128, tileN = (size_t)blockIdx.x * 128;
    const int frow = lane & 15, fcol = (lane >> 4) * 8;
    f32x4 acc[4][4] = {};
    for (int k0 = 0; k0 < K; k0 += 32) {
        __syncthreads();
#pragma unroll
        for (int it = 0; it < 4; ++it) {          // A: 1024 float4s / 256 thr
            int idx = it * 256 + tid;
            int m = idx >> 3, c4 = (idx & 7) * 4;
            float4 v = *(const float4*)(X + (tileM + m) * (size_t)K + k0 + c4);
            sA[m * 32 + c4 + 0] = f32_to_bf16(v.x);
            sA[m * 32 + c4 + 1] = f32_to_bf16(v.y);
            sA[m * 32 + c4 + 2] = f32_to_bf16(v.z);
            sA[m * 32 + c4 + 3] = f32_to_bf16(v.w);
        }
#pragma unroll
        for (int it = 0; it < 16; ++it) {         // B: transpose on the fly
            int idx = it * 256 + tid;
            int k = idx >> 7, n = idx & 127;
            float v = Wt[(size_t)(k0 + k) * N + tileN + n];
            sB[n * 32 + k] = f32_to_bf16(v);
        }
        __syncthreads();
        s16x8 af[4], bfr[4];
#pragma unroll
        for (int i = 0; i < 4; ++i)
            af[i] = *(const s16x8*)(sA + (wm + i * 16 + frow) * 32 + fcol);
#pragma unroll
        for (int j = 0; j < 4; ++j)
            bfr[j] = *(const s16x8*)(sB + (wn + j * 16 + frow) * 32 + fcol);
#pragma unroll
        for (int i = 0; i < 4; ++i)
#pragma unroll
            for (int j = 0; j < 4; ++j)
                acc[i][j] = __builtin_amdgcn_mfma_f32_16x16x32_bf16(
                    af[i], bfr[j], acc[i][j], 0, 0, 0);
    }
#pragma unroll
    for (int i = 0; i < 4; ++i)
#pragma unroll
        for (int j = 0; j < 4; ++j) {
            size_t row = tileM + wm + i * 16 + (lane >> 4) * 4;
            size_t col = tileN + wn + j * 16 + (lane & 15);
#pragma unroll
            for (int r = 0; r < 4; ++r)
                C[(row + r) * N + col] = acc[i][j][r];
        }
}

extern "C" void kernel_launch(void* const* d_in, const int* in_sizes, int n_in,
                              void* d_out, int out_size, void* d_ws, size_t ws_size,
                              hipStream_t stream) {
    const float* x   = (const float*)d_in[0];
    const float* w_t = (const float*)d_in[4];   // (K,N) == dequantized W^T, bit-exact
    float* out = (float*)d_out;
    const int K = K_DIM, N = N_DIM;
    const int M = in_sizes[0] / K;              // 8192
    const size_t need = (size_t)M * K * 2 + (size_t)N * K * 2;  // 96 MB
    if (ws_size >= need) {
        unsigned short* xb = (unsigned short*)d_ws;
        unsigned short* wb = xb + (size_t)M * K;
        int n8 = M * K / 8;
        hipLaunchKernelGGL(cvt_bf16_k, dim3((n8 + 255) / 256), dim3(256), 0, stream,
                           x, xb, n8);
        hipLaunchKernelGGL(transpose_cvt_k, dim3(N / 64, K / 64), dim3(256), 0, stream,
                           w_t, wb);
        hipLaunchKernelGGL(gemm_bf16_k, dim3(N / 128, M / 128), dim3(256), 0, stream,
                           xb, wb, out, M);
    } else {
        hipLaunchKernelGGL(gemm_f32_k, dim3(N / 128, M / 128), dim3(256), 0, stream,
                           x, w_t, out, M);
    }
}

// Round 3
// 625.173 us; speedup vs baseline: 1.0997x; 1.0997x over previous
//
#include <hip/hip_runtime.h>
#include <stdint.h>

#define K_DIM 4096
#define N_DIM 4096
#define KS_DIM (K_DIM / 32)   // 128 k-steps
#define NT_DIM (N_DIM / 16)   // 256 n-tiles

typedef __attribute__((ext_vector_type(8))) short s16x8;
typedef __attribute__((ext_vector_type(4))) float f32x4;

static __device__ __forceinline__ unsigned short f32_to_bf16(float f) {
    union { float f; unsigned int u; } v; v.f = f;
    unsigned int u = v.u;
    u += 0x7FFFu + ((u >> 16) & 1u);   // RNE; inputs finite
    return (unsigned short)(u >> 16);
}

// ---------------------------------------------------------------------------
// Fragment pack layout (both operands): for 16x16x32 bf16 MFMA, lane L holds
// op[m_or_n = L&15][k = (L>>4)*8 + j], j=0..7.  We store each (tile, k-step)
// fragment as 64 lane-chunks of 16 B, in lane order:
//   pack[ ((ks * T + t) * 64 + L) * 8 ]   (T = M/16 or N/16, t = tile index)
// => LDS image after global_load_lds is base + L*16  => fragment ds_read is
//    perfectly linear (conflict-free), and B can be read fragment-direct
//    from global with coalesced dwordx4.
// ---------------------------------------------------------------------------

// x (M,K) f32 -> A-pack. One wave per (ks, mt) tile.
extern "C" __global__ void pack_x_k(const float* __restrict__ in,
                                    unsigned short* __restrict__ out, int MT) {
    int wid = blockIdx.x * 4 + (threadIdx.x >> 6);
    int lane = threadIdx.x & 63;
    int mt = wid % MT, ks = wid / MT;
    int r = lane & 15, q = lane >> 4;
    const float* src = in + (size_t)(mt * 16 + r) * K_DIM + ks * 32 + q * 8;
    float4 a = *(const float4*)src;
    float4 b = *(const float4*)(src + 4);
    s16x8 o;
    o[0] = (short)f32_to_bf16(a.x); o[1] = (short)f32_to_bf16(a.y);
    o[2] = (short)f32_to_bf16(a.z); o[3] = (short)f32_to_bf16(a.w);
    o[4] = (short)f32_to_bf16(b.x); o[5] = (short)f32_to_bf16(b.y);
    o[6] = (short)f32_to_bf16(b.z); o[7] = (short)f32_to_bf16(b.w);
    *(s16x8*)(out + ((size_t)wid * 64 + lane) * 8) = o;
}

// w_t (K,N) f32 -> B-pack via LDS transpose. Block handles 64k x 64n.
extern "C" __global__ void pack_w_k(const float* __restrict__ in,
                                    unsigned short* __restrict__ out) {
    __shared__ __align__(16) unsigned short tile[64][72];  // [n_local][k_local]
    int n0 = blockIdx.x * 64, k0 = blockIdx.y * 64;
    int t = threadIdx.x;
    int tr = t >> 4, tc = (t & 15) * 4;
#pragma unroll
    for (int i = 0; i < 4; ++i) {
        int k = tr + i * 16;
        float4 v = *(const float4*)(in + (size_t)(k0 + k) * N_DIM + n0 + tc);
        tile[tc + 0][k] = f32_to_bf16(v.x);
        tile[tc + 1][k] = f32_to_bf16(v.y);
        tile[tc + 2][k] = f32_to_bf16(v.z);
        tile[tc + 3][k] = f32_to_bf16(v.w);
    }
    __syncthreads();
    // 8 fragments per block: f = h*4 + ntl  (h = k-half, ntl = n-tile local)
    int f = t >> 5, h = f >> 2, ntl = f & 3;
    int ks = blockIdx.y * 2 + h;
    int nt = blockIdx.x * 4 + ntl;
    unsigned short* dst = out + ((size_t)(ks * NT_DIM + nt) * 64) * 8;
#pragma unroll
    for (int u = 0; u < 2; ++u) {
        int c = (t & 31) * 2 + u;            // lane-chunk index 0..63
        int r = c & 15, q = c >> 4;
        s16x8 o = *(const s16x8*)&tile[ntl * 16 + r][h * 32 + q * 8];
        *(s16x8*)(dst + (size_t)c * 8) = o;
    }
}

__device__ __forceinline__ void async_cp16(const unsigned short* g, unsigned short* l) {
    __builtin_amdgcn_global_load_lds(
        (const __attribute__((address_space(1))) unsigned int*)g,
        (__attribute__((address_space(3))) unsigned int*)l, 16, 0, 0);
}

// GEMM on packed operands. 128x128 tile, BK=32; A via LDS (8 KB only),
// B fragment-direct from global. 4 waves, each 4x4 of 16x16x32 MFMA.
extern "C" __global__ __launch_bounds__(256)
void gemm_pk(const unsigned short* __restrict__ Ap,
             const unsigned short* __restrict__ Bp,
             float* __restrict__ C, int M) {
    const int N = N_DIM;
    const int MT = M >> 4;
    __shared__ __align__(16) unsigned short sA[8 * 512];   // 8 KB
    const int tid = threadIdx.x;
    const int wave = tid >> 6, lane = tid & 63;
    const int wm = (wave >> 1) * 64, wn = (wave & 1) * 64;
    f32x4 acc[4][4] = {};

    // A staging: wave stages mt-local tiles {2w, 2w+1}; per-lane global src,
    // wave-uniform LDS dst (HW scatters lane*16).
    const unsigned short* gA =
        Ap + ((size_t)(blockIdx.y * 8 + wave * 2) * 64 + lane) * 8;
    unsigned short* lA = sA + (wave * 2) * 512;            // wave-uniform
    // B fragments: 4 n-tiles for this wave's wn.
    const unsigned short* gB =
        Bp + ((size_t)(blockIdx.x * 8 + (wave & 1) * 4) * 64 + lane) * 8;
    // fragment read base (linear in lane => conflict-free)
    const unsigned short* fA = sA + (wave >> 1) * 4 * 512 + lane * 8;

    for (int ks = 0; ks < KS_DIM; ++ks) {
        __syncthreads();                    // protect sA from previous reads
        async_cp16(gA, lA);
        async_cp16(gA + 512, lA + 512);     // +512 elems = next m-tile (BUGFIX)
        gA += (size_t)MT * 512;
        s16x8 bf[4];
#pragma unroll
        for (int j = 0; j < 4; ++j)
            bf[j] = *(const s16x8*)(gB + (size_t)j * 512);
        gB += (size_t)NT_DIM * 512;
        __syncthreads();                    // drains cp + makes sA visible
        s16x8 af[4];
#pragma unroll
        for (int i = 0; i < 4; ++i)
            af[i] = *(const s16x8*)(fA + i * 512);
#pragma unroll
        for (int i = 0; i < 4; ++i)
#pragma unroll
            for (int j = 0; j < 4; ++j)
                acc[i][j] = __builtin_amdgcn_mfma_f32_16x16x32_bf16(
                    af[i], bf[j], acc[i][j], 0, 0, 0);
    }
    // epilogue: C/D layout col=lane&15, row=(lane>>4)*4+reg (m89-verified)
    const size_t tileM = (size_t)blockIdx.y * 128, tileN = (size_t)blockIdx.x * 128;
#pragma unroll
    for (int i = 0; i < 4; ++i)
#pragma unroll
        for (int j = 0; j < 4; ++j) {
            size_t row = tileM + wm + i * 16 + (lane >> 4) * 4;
            size_t col = tileN + wn + j * 16 + (lane & 15);
#pragma unroll
            for (int r = 0; r < 4; ++r)
                C[(row + r) * N + col] = acc[i][j][r];
        }
}

// ---- fallback (ws too small): convert f32->bf16 inline while staging ----
extern "C" __global__ __launch_bounds__(256)
void gemm_f32_k(const float* __restrict__ X,   // (M,K)
                const float* __restrict__ Wt,  // (K,N)
                float* __restrict__ C, int M) {
    const int K = K_DIM, N = N_DIM;
    __shared__ __align__(16) unsigned short sA[128 * 32];
    __shared__ __align__(16) unsigned short sB[128 * 32];
    const int tid = threadIdx.x;
    const int wave = tid >> 6, lane = tid & 63;
    const int wm = (wave >> 1) * 64, wn = (wave & 1) * 64;
    const size_t tileM = (size_t)blockIdx.y * 128, tileN = (size_t)blockIdx.x * 128;
    const int frow = lane & 15, fcol = (lane >> 4) * 8;
    f32x4 acc[4][4] = {};
    for (int k0 = 0; k0 < K; k0 += 32) {
        __syncthreads();
#pragma unroll
        for (int it = 0; it < 4; ++it) {
            int idx = it * 256 + tid;
            int m = idx >> 3, c4 = (idx & 7) * 4;
            float4 v = *(const float4*)(X + (tileM + m) * (size_t)K + k0 + c4);
            sA[m * 32 + c4 + 0] = f32_to_bf16(v.x);
            sA[m * 32 + c4 + 1] = f32_to_bf16(v.y);
            sA[m * 32 + c4 + 2] = f32_to_bf16(v.z);
            sA[m * 32 + c4 + 3] = f32_to_bf16(v.w);
        }
#pragma unroll
        for (int it = 0; it < 16; ++it) {
            int idx = it * 256 + tid;
            int k = idx >> 7, n = idx & 127;
            float v = Wt[(size_t)(k0 + k) * N + tileN + n];
            sB[n * 32 + k] = f32_to_bf16(v);
        }
        __syncthreads();
        s16x8 af[4], bfr[4];
#pragma unroll
        for (int i = 0; i < 4; ++i)
            af[i] = *(const s16x8*)(sA + (wm + i * 16 + frow) * 32 + fcol);
#pragma unroll
        for (int j = 0; j < 4; ++j)
            bfr[j] = *(const s16x8*)(sB + (wn + j * 16 + frow) * 32 + fcol);
#pragma unroll
        for (int i = 0; i < 4; ++i)
#pragma unroll
            for (int j = 0; j < 4; ++j)
                acc[i][j] = __builtin_amdgcn_mfma_f32_16x16x32_bf16(
                    af[i], bfr[j], acc[i][j], 0, 0, 0);
    }
#pragma unroll
    for (int i = 0; i < 4; ++i)
#pragma unroll
        for (int j = 0; j < 4; ++j) {
            size_t row = tileM + wm + i * 16 + (lane >> 4) * 4;
            size_t col = tileN + wn + j * 16 + (lane & 15);
#pragma unroll
            for (int r = 0; r < 4; ++r)
                C[(row + r) * N + col] = acc[i][j][r];
        }
}

extern "C" void kernel_launch(void* const* d_in, const int* in_sizes, int n_in,
                              void* d_out, int out_size, void* d_ws, size_t ws_size,
                              hipStream_t stream) {
    const float* x   = (const float*)d_in[0];
    const float* w_t = (const float*)d_in[4];   // (K,N) dequantized W^T, bit-exact
    float* out = (float*)d_out;
    const int K = K_DIM, N = N_DIM;
    const int M = in_sizes[0] / K;              // 8192
    const int MT = M / 16;
    const size_t need = (size_t)M * K * 2 + (size_t)N * K * 2;  // 96 MB
    if (ws_size >= need) {
        unsigned short* ap = (unsigned short*)d_ws;
        unsigned short* bp = ap + (size_t)M * K;
        int nwave = KS_DIM * MT;  // one wave per A fragment-tile
        hipLaunchKernelGGL(pack_x_k, dim3(nwave / 4), dim3(256), 0, stream,
                           x, ap, MT);
        hipLaunchKernelGGL(pack_w_k, dim3(N / 64, K / 64), dim3(256), 0, stream,
                           w_t, bp);
        hipLaunchKernelGGL(gemm_pk, dim3(N / 128, M / 128), dim3(256), 0, stream,
                           ap, bp, out, M);
    } else {
        hipLaunchKernelGGL(gemm_f32_k, dim3(N / 128, M / 128), dim3(256), 0, stream,
                           x, w_t, out, M);
    }
}